// Round 2
// baseline (425.457 us; speedup 1.0000x reference)
//
#include <hip/hip_runtime.h>
#include <hip/hip_bf16.h>

// Problem shapes (fixed by the reference):
//   n_atoms=50000, hidden=32, num_irreps=16, out_ch=32, n_edges=800000
//   W is (512, 32) with flat index (h*16+i)*32 + c == h*512 + (i*32+c),
//   so P = nf @ W viewed as (32 x 512) needs NO reindexing.

#define HIDDEN 32
#define IRREPS 16
#define OUTCH  32
#define PROW   512            // IRREPS*OUTCH, elements per atom in P
#define PROW2  256            // PROW/2 (bf162 pairs)

// ---------------- Kernel 1: P[a, j] = sum_h nf[a,h] * W[h*512 + j], bf16 ----
__global__ void compute_P_kernel(const float* __restrict__ nf,
                                 const float* __restrict__ W,
                                 __hip_bfloat162* __restrict__ P2) {
    const int a  = blockIdx.x;          // one atom per 256-thread block
    const int jj = threadIdx.x;         // bf162 pair index: columns 2jj, 2jj+1
    const float*  nfa = nf + a * HIDDEN;   // uniform across block -> s_loads
    const float2* W2  = (const float2*)W;  // viewed 32 x 256 float2, L2-resident
    float acc0 = 0.f, acc1 = 0.f;
#pragma unroll
    for (int h = 0; h < HIDDEN; ++h) {
        float2 w = W2[h * PROW2 + jj];
        float  n = nfa[h];
        acc0 = fmaf(n, w.x, acc0);
        acc1 = fmaf(n, w.y, acc1);
    }
    __hip_bfloat162 pk;
    pk.x = __float2bfloat16(acc0);
    pk.y = __float2bfloat16(acc1);
    P2[a * PROW2 + jj] = pk;
}

// ---------------- Kernel 2: out[a, c] = b[c] ------------------------------
__global__ void init_out_kernel(float* __restrict__ out,
                                const float* __restrict__ b, int total) {
    int idx = blockIdx.x * blockDim.x + threadIdx.x;
    if (idx < total) out[idx] = b[idx & (OUTCH - 1)];
}

// ---------------- Kernel 3: per-edge Y . P[src] -> atomic into out[tgt] ----
// 16 threads per edge; thread `sub` owns output channels (2*sub, 2*sub+1).
__global__ void edge_scatter_kernel(const float* __restrict__ ev,
                                    const int* __restrict__ ei,
                                    const __hip_bfloat162* __restrict__ P2,
                                    float* __restrict__ out, int n_edges) {
    const int tid = blockIdx.x * blockDim.x + threadIdx.x;
    const int e   = tid >> 4;
    if (e >= n_edges) return;
    const int sub = tid & 15;

    const int src = ei[e];
    const int tgt = ei[n_edges + e];

    const float vx = ev[3 * e + 0];
    const float vy = ev[3 * e + 1];
    const float vz = ev[3 * e + 2];
    const float r    = sqrtf(vx * vx + vy * vy + vz * vz);
    const float rinv = 1.0f / fmaxf(r, 1e-12f);
    const float x = vx * rinv, y = vy * rinv, z = vz * rinv;
    const float x2 = x * x, y2 = y * y, z2 = z * z;

    float Y[IRREPS];
    Y[0]  = 0.28209479177387814f;
    Y[1]  = 0.4886025119029199f * y;
    Y[2]  = 0.4886025119029199f * z;
    Y[3]  = 0.4886025119029199f * x;
    Y[4]  = 1.0925484305920792f * x * y;
    Y[5]  = 1.0925484305920792f * y * z;
    Y[6]  = 0.31539156525252005f * (3.0f * z2 - 1.0f);
    Y[7]  = 1.0925484305920792f * x * z;
    Y[8]  = 0.5462742152960396f * (x2 - y2);
    Y[9]  = 0.5900435899266435f * y * (3.0f * x2 - y2);
    Y[10] = 2.890611442640554f * x * y * z;
    Y[11] = 0.4570457994644658f * y * (5.0f * z2 - 1.0f);
    Y[12] = 0.3731763325901154f * z * (5.0f * z2 - 3.0f);
    Y[13] = 0.4570457994644658f * x * (5.0f * z2 - 1.0f);
    Y[14] = 1.445305721320277f * z * (x2 - y2);
    Y[15] = 0.5900435899266435f * x * (x2 - 3.0f * y2);

    const __hip_bfloat162* Pa = P2 + src * PROW2 + sub;
    float m0 = 0.f, m1 = 0.f;
#pragma unroll
    for (int i = 0; i < IRREPS; ++i) {
        float2 p = __bfloat1622float2(Pa[i * (OUTCH / 2)]);
        m0 = fmaf(Y[i], p.x, m0);
        m1 = fmaf(Y[i], p.y, m1);
    }

    float* o = out + tgt * OUTCH + 2 * sub;
    unsafeAtomicAdd(o,     m0);   // hardware global_atomic_add_f32
    unsafeAtomicAdd(o + 1, m1);
}

// ---------------- launch ---------------------------------------------------
extern "C" void kernel_launch(void* const* d_in, const int* in_sizes, int n_in,
                              void* d_out, int out_size, void* d_ws, size_t ws_size,
                              hipStream_t stream) {
    const float* nf = (const float*)d_in[0];   // (n_atoms, 32) f32
    const float* ev = (const float*)d_in[1];   // (n_edges, 3)  f32
    const int*   ei = (const int*)d_in[2];     // (2, n_edges)  int32
    const float* W  = (const float*)d_in[3];   // (512, 32)     f32
    const float* b  = (const float*)d_in[4];   // (32,)         f32
    float* out = (float*)d_out;                // (n_atoms, 32) f32

    const int n_atoms = in_sizes[0] / HIDDEN;
    const int n_edges = in_sizes[1] / 3;

    __hip_bfloat162* P2 = (__hip_bfloat162*)d_ws;  // n_atoms * 256 bf162 = 51.2 MB

    compute_P_kernel<<<n_atoms, PROW2, 0, stream>>>(nf, W, P2);

    const int out_total = n_atoms * OUTCH;
    init_out_kernel<<<(out_total + 255) / 256, 256, 0, stream>>>(out, b, out_total);

    const long long work = (long long)n_edges * 16;
    edge_scatter_kernel<<<(int)((work + 255) / 256), 256, 0, stream>>>(
        ev, ei, P2, out, n_edges);
}

// Round 3
// 293.762 us; speedup vs baseline: 1.4483x; 1.4483x over previous
//
#include <hip/hip_runtime.h>
#include <hip/hip_bf16.h>

// Shapes: n_atoms=50000, hidden=32, num_irreps=16, out_ch=32, n_edges=800000
// W (512,32): flat index (h*16+i)*32+c == h*512 + (i*32+c).
// P[a, i, c] = sum_h nf[a,h] * W[h*512 + i*32 + c], stored bf16 in layout
// [a][c][i] (c-major) so the edge kernel can gather 64 B/lane contiguously.

#define HIDDEN 32
#define IRREPS 16
#define OUTCH  32
#define PPAIRS 256          // bf162 pairs per atom (512 bf16)
#define APB    64           // atoms per block in compute_P

// ---------------- Kernel 1: P (bf16, [a][c][i] layout), W in registers -----
__global__ __launch_bounds__(256)
void compute_P_kernel(const float* __restrict__ nf,
                      const float* __restrict__ W,
                      __hip_bfloat162* __restrict__ P2, int n_atoms) {
    const int t  = threadIdx.x;
    const int c  = t >> 3;                 // 0..31  output channel
    const int ip = t & 7;                  // 0..7   i-pair (i=2ip, 2ip+1)
    const int j0 = (2 * ip) * OUTCH + c;   // flat W column for i=2ip
    const int j1 = j0 + OUTCH;             // i=2ip+1

    float w0[HIDDEN], w1[HIDDEN];
#pragma unroll
    for (int h = 0; h < HIDDEN; ++h) {
        w0[h] = W[h * 512 + j0];
        w1[h] = W[h * 512 + j1];
    }

    const int a0 = blockIdx.x * APB;
    const int a1 = min(a0 + APB, n_atoms);
    for (int a = a0; a < a1; ++a) {
        const float* nfa = nf + a * HIDDEN;   // uniform -> scalar loads
        float acc0 = 0.f, acc1 = 0.f;
#pragma unroll
        for (int h = 0; h < HIDDEN; ++h) {
            const float n = nfa[h];
            acc0 = fmaf(n, w0[h], acc0);
            acc1 = fmaf(n, w1[h], acc1);
        }
        __hip_bfloat162 pk;
        pk.x = __float2bfloat16(acc0);
        pk.y = __float2bfloat16(acc1);
        // pair index within atom: c*8 + ip == t  (c-major layout)
        P2[a * PPAIRS + t] = pk;
    }
}

// ---------------- Kernel 2: out[a, c] = b[c] ------------------------------
__global__ void init_out_kernel(float* __restrict__ out,
                                const float* __restrict__ b, int total) {
    int idx = blockIdx.x * blockDim.x + threadIdx.x;
    if (idx < total) out[idx] = b[idx & (OUTCH - 1)];
}

// ---------------- Kernel 3: per-edge Y . P[src] -> atomic into out[tgt] ----
// 16 threads per edge; thread `sub` owns channels c0=2sub, c1=2sub+1 and
// gathers its 64 B slice (2 channels x 16 bf16) as 4x dwordx4.
__device__ __forceinline__ float2 bf2f2(unsigned u) {
    return __bfloat1622float2(*(const __hip_bfloat162*)&u);
}

__global__ __launch_bounds__(256)
void edge_scatter_kernel(const float* __restrict__ ev,
                         const int* __restrict__ ei,
                         const __hip_bfloat162* __restrict__ P2,
                         float* __restrict__ out, int n_edges) {
    const int tid = blockIdx.x * blockDim.x + threadIdx.x;
    const int e   = tid >> 4;
    if (e >= n_edges) return;
    const int sub = tid & 15;

    const int src = ei[e];
    const int tgt = ei[n_edges + e];

    const float vx = ev[3 * e + 0];
    const float vy = ev[3 * e + 1];
    const float vz = ev[3 * e + 2];
    const float r    = sqrtf(vx * vx + vy * vy + vz * vz);
    const float rinv = 1.0f / fmaxf(r, 1e-12f);
    const float x = vx * rinv, y = vy * rinv, z = vz * rinv;
    const float x2 = x * x, y2 = y * y, z2 = z * z;

    float Y[IRREPS];
    Y[0]  = 0.28209479177387814f;
    Y[1]  = 0.4886025119029199f * y;
    Y[2]  = 0.4886025119029199f * z;
    Y[3]  = 0.4886025119029199f * x;
    Y[4]  = 1.0925484305920792f * x * y;
    Y[5]  = 1.0925484305920792f * y * z;
    Y[6]  = 0.31539156525252005f * (3.0f * z2 - 1.0f);
    Y[7]  = 1.0925484305920792f * x * z;
    Y[8]  = 0.5462742152960396f * (x2 - y2);
    Y[9]  = 0.5900435899266435f * y * (3.0f * x2 - y2);
    Y[10] = 2.890611442640554f * x * y * z;
    Y[11] = 0.4570457994644658f * y * (5.0f * z2 - 1.0f);
    Y[12] = 0.3731763325901154f * z * (5.0f * z2 - 3.0f);
    Y[13] = 0.4570457994644658f * x * (5.0f * z2 - 1.0f);
    Y[14] = 1.445305721320277f * z * (x2 - y2);
    Y[15] = 0.5900435899266435f * x * (x2 - 3.0f * y2);

    // 64 B contiguous: pairs [16*sub .. 16*sub+15] of atom `src`
    const uint4* q = (const uint4*)(P2 + src * PPAIRS + 16 * sub);
    const uint4 A = q[0];   // c0, i 0..7
    const uint4 B = q[1];   // c0, i 8..15
    const uint4 C = q[2];   // c1, i 0..7
    const uint4 D = q[3];   // c1, i 8..15

    float m0 = 0.f, m1 = 0.f;
    {
        float2 p;
        p = bf2f2(A.x); m0 = fmaf(Y[0],  p.x, m0); m0 = fmaf(Y[1],  p.y, m0);
        p = bf2f2(A.y); m0 = fmaf(Y[2],  p.x, m0); m0 = fmaf(Y[3],  p.y, m0);
        p = bf2f2(A.z); m0 = fmaf(Y[4],  p.x, m0); m0 = fmaf(Y[5],  p.y, m0);
        p = bf2f2(A.w); m0 = fmaf(Y[6],  p.x, m0); m0 = fmaf(Y[7],  p.y, m0);
        p = bf2f2(B.x); m0 = fmaf(Y[8],  p.x, m0); m0 = fmaf(Y[9],  p.y, m0);
        p = bf2f2(B.y); m0 = fmaf(Y[10], p.x, m0); m0 = fmaf(Y[11], p.y, m0);
        p = bf2f2(B.z); m0 = fmaf(Y[12], p.x, m0); m0 = fmaf(Y[13], p.y, m0);
        p = bf2f2(B.w); m0 = fmaf(Y[14], p.x, m0); m0 = fmaf(Y[15], p.y, m0);
        p = bf2f2(C.x); m1 = fmaf(Y[0],  p.x, m1); m1 = fmaf(Y[1],  p.y, m1);
        p = bf2f2(C.y); m1 = fmaf(Y[2],  p.x, m1); m1 = fmaf(Y[3],  p.y, m1);
        p = bf2f2(C.z); m1 = fmaf(Y[4],  p.x, m1); m1 = fmaf(Y[5],  p.y, m1);
        p = bf2f2(C.w); m1 = fmaf(Y[6],  p.x, m1); m1 = fmaf(Y[7],  p.y, m1);
        p = bf2f2(D.x); m1 = fmaf(Y[8],  p.x, m1); m1 = fmaf(Y[9],  p.y, m1);
        p = bf2f2(D.y); m1 = fmaf(Y[10], p.x, m1); m1 = fmaf(Y[11], p.y, m1);
        p = bf2f2(D.z); m1 = fmaf(Y[12], p.x, m1); m1 = fmaf(Y[13], p.y, m1);
        p = bf2f2(D.w); m1 = fmaf(Y[14], p.x, m1); m1 = fmaf(Y[15], p.y, m1);
    }

    float* o = out + tgt * OUTCH + 2 * sub;
    unsafeAtomicAdd(o,     m0);   // hardware global_atomic_add_f32
    unsafeAtomicAdd(o + 1, m1);
}

// ---------------- launch ---------------------------------------------------
extern "C" void kernel_launch(void* const* d_in, const int* in_sizes, int n_in,
                              void* d_out, int out_size, void* d_ws, size_t ws_size,
                              hipStream_t stream) {
    const float* nf = (const float*)d_in[0];   // (n_atoms, 32) f32
    const float* ev = (const float*)d_in[1];   // (n_edges, 3)  f32
    const int*   ei = (const int*)d_in[2];     // (2, n_edges)  int32
    const float* W  = (const float*)d_in[3];   // (512, 32)     f32
    const float* b  = (const float*)d_in[4];   // (32,)         f32
    float* out = (float*)d_out;                // (n_atoms, 32) f32

    const int n_atoms = in_sizes[0] / HIDDEN;
    const int n_edges = in_sizes[1] / 3;

    __hip_bfloat162* P2 = (__hip_bfloat162*)d_ws;  // 51.2 MB

    compute_P_kernel<<<(n_atoms + APB - 1) / APB, 256, 0, stream>>>(nf, W, P2, n_atoms);

    const int out_total = n_atoms * OUTCH;
    init_out_kernel<<<(out_total + 255) / 256, 256, 0, stream>>>(out, b, out_total);

    const long long work = (long long)n_edges * 16;
    edge_scatter_kernel<<<(int)((work + 255) / 256), 256, 0, stream>>>(
        ev, ei, P2, out, n_edges);
}